// Round 6
// baseline (198.660 us; speedup 1.0000x reference)
//
#include <hip/hip_runtime.h>
#include <math.h>

#define HH 28
#define WW 28
#define NPIX 784
#define MMAX 785
#define NMAXP 100
#define NTH 512
#define BCAP 512       // max basins (theory bound: H1 4-conn <= 393, H0 8-conn <= 196)
#define HSZ 4096
#define HMASK 4095
#define ECAP 2048      // deduped basin-pair edges (random ~470; planar-ish bound ~1200)
#define PCAP 512
#define SELCAP 512
// Essential-death sentinel: must stay FINITE after the harness's bf16
// round-trip (FLT_MAX rounds to +inf in bf16 -> inf-inf=NaN). 1e30 is safe.
#define ESS_DEATH 1e30f

// monotone float<->u32 (totally ordered as unsigned)
__device__ __forceinline__ unsigned f2mono(float f) {
    unsigned u = __float_as_uint(f);
    return (u & 0x80000000u) ? ~u : (u | 0x80000000u);
}
__device__ __forceinline__ float mono2f(unsigned m) {
    unsigned u = (m & 0x80000000u) ? (m ^ 0x80000000u) : ~m;
    return __uint_as_float(u);
}

// neighbors of cell c; nb[k] = -1 if invalid.
// which==0: 8-conn. which==1: 4-conn + virtual boundary node NPIX.
__device__ __forceinline__ int get_nbrs(int c, int which, int* nb) {
    int ci = c / WW;
    int cj = c - ci * WW;
    if (which == 0) {
        const int di[8] = {-1,-1,-1, 0, 0, 1, 1, 1};
        const int dj[8] = {-1, 0, 1,-1, 1,-1, 0, 1};
        #pragma unroll
        for (int k = 0; k < 8; ++k) {
            int ii = ci + di[k], jj = cj + dj[k];
            nb[k] = (ii >= 0 && ii < HH && jj >= 0 && jj < WW) ? (ii * WW + jj) : -1;
        }
        return 8;
    } else {
        const int di[4] = {-1, 1, 0, 0};
        const int dj[4] = { 0, 0,-1, 1};
        #pragma unroll
        for (int k = 0; k < 4; ++k) {
            int ii = ci + di[k], jj = cj + dj[k];
            nb[k] = (ii >= 0 && ii < HH && jj >= 0 && jj < WW) ? (ii * WW + jj) : -1;
        }
        nb[4] = (ci == 0 || ci == HH - 1 || cj == 0 || cj == WW - 1) ? NPIX : -1;
        return 5;
    }
}

// One block per (sample, dim): blk = s*2 + which.
// which==0 -> H0 (8-conn sublevel on x); which==1 -> H1 via superlevel
// (sublevel on -x, 4-conn, virtual -inf boundary node).
__global__ __launch_bounds__(NTH)
void pd_kernel(const float* __restrict__ x, float* __restrict__ out)
{
    const int blk   = blockIdx.x;
    const int s     = blk >> 1;
    const int which = blk & 1;
    const int tid   = threadIdx.x;
    const int M     = NPIX + which;

    __shared__ float vals[MMAX];
    __shared__ int   dA[MMAX];                  // steepest-descent / basin root cell
    __shared__ int   dB[MMAX];                  // jump scratch, then cid at root cells
    __shared__ int   cido[MMAX];                // per-cell compact basin id
    __shared__ unsigned long long rootsSort[BCAP]; // (valmono<<32)|cell -> sorted = cid order
    __shared__ unsigned bval[BCAP];             // basin-min valmono per cid
    __shared__ unsigned hkey[HSZ];              // hash: pk+1 (0 = empty)
    __shared__ unsigned hval[HSZ];              // hash: min weight (monotone u32)
    __shared__ unsigned long long e2[ECAP];     // (wmono<<18)|pk ; reused for selection
    __shared__ float pb[PCAP], pdd[PCAP];       // recorded pairs (output space)
    __shared__ int   bcnt, scnt, npairs;

    if (tid == 0) { bcnt = 0; scnt = 0; npairs = 0; }
    for (int i = tid; i < HSZ; i += NTH) { hkey[i] = 0u; hval[i] = 0xFFFFFFFFu; }
    for (int i = tid; i < BCAP; i += NTH) rootsSort[i] = ~0ull;
    for (int i = tid; i < NPIX; i += NTH) {
        float v = x[s * NPIX + i];
        vals[i] = which ? -v : v;
    }
    if (tid == 0 && which) vals[NPIX] = -INFINITY;
    __syncthreads();

    // ---- steepest-descent pointer: lex-min (val, idx) over {self} U nbrs ----
    for (int i = tid; i < M; i += NTH) {
        int best = i; float bv = vals[i];
        if (i < NPIX) {
            int nb[8];
            int K = get_nbrs(i, which, nb);
            for (int k = 0; k < K; ++k) {
                int n = nb[k]; if (n < 0) continue;
                float vn = vals[n];
                if (vn < bv || (vn == bv && n < best)) { bv = vn; best = n; }
            }
        }
        dA[i] = best;   // == i iff local min (basin root)
    }
    __syncthreads();

    // ---- pointer jumping: 10 compositions -> covers depth 2^10 >= 784 ----
    for (int rnd = 0; rnd < 5; ++rnd) {
        for (int i = tid; i < M; i += NTH) dB[i] = dA[dA[i]];
        __syncthreads();
        for (int i = tid; i < M; i += NTH) dA[i] = dB[dB[i]];
        __syncthreads();
    }

    // ---- collect basin roots, sort by (valmono, cell) -> cid = value order ----
    for (int i = tid; i < M; i += NTH) {
        if (dA[i] == i) {
            int j = atomicAdd(&bcnt, 1);
            if (j < BCAP)
                rootsSort[j] = ((unsigned long long)f2mono(vals[i]) << 32) | (unsigned)i;
        }
    }
    __syncthreads();
    const int B = bcnt;
    int LENB = 1; while (LENB < B) LENB <<= 1;
    for (int k = 2; k <= LENB; k <<= 1)
        for (int j = k >> 1; j > 0; j >>= 1) {
            for (int t = tid; t < LENB; t += NTH) {
                int l = t ^ j;
                if (l > t) {
                    unsigned long long a = rootsSort[t], b = rootsSort[l];
                    if ((a > b) == ((t & k) == 0)) { rootsSort[t] = b; rootsSort[l] = a; }
                }
            }
            __syncthreads();
        }
    for (int b = tid; b < B; b += NTH) {
        unsigned long long v = rootsSort[b];
        if (v != ~0ull) {
            int cell = (int)(v & 0xFFFFFFFFull);
            dB[cell] = b;                       // cid at root cell
            bval[b]  = (unsigned)(v >> 32);
        }
    }
    __syncthreads();
    for (int i = tid; i < M; i += NTH) cido[i] = dB[dA[i]];
    __syncthreads();

    // ---- cross-basin edges -> hash dedup (min weight per basin pair) ----
    for (int c = tid; c < NPIX; c += NTH) {
        float vc = vals[c];
        int bc = cido[c];
        int nb[8];
        int K = get_nbrs(c, which, nb);
        unsigned wm = f2mono(vc);
        for (int k = 0; k < K; ++k) {
            int n = nb[k]; if (n < 0) continue;
            float vn = vals[n];
            if (!(vn < vc || (vn == vc && n < c))) continue;  // emit from higher endpoint
            int bn = cido[n];
            if (bn == bc) continue;
            unsigned c0 = (unsigned)(bc < bn ? bc : bn);
            unsigned c1 = (unsigned)(bc < bn ? bn : bc);
            unsigned pk  = (c0 << 9) | c1;       // cids < 512 -> 18 bits
            unsigned key = pk + 1u;
            unsigned slot = (pk * 0x9E3779B1u) >> 20;  // 12-bit hash
            for (;;) {
                unsigned prev = atomicCAS(&hkey[slot], 0u, key);
                if (prev == 0u || prev == key) { atomicMin(&hval[slot], wm); break; }
                slot = (slot + 1) & HMASK;
            }
        }
    }
    __syncthreads();

    // ---- gather survivors ----
    for (int i = tid; i < HSZ; i += NTH) {
        unsigned key = hkey[i];
        if (key) {
            int j = atomicAdd(&scnt, 1);
            if (j < ECAP)
                e2[j] = ((unsigned long long)hval[i] << 18) | (unsigned long long)(key - 1u);
        }
    }
    __syncthreads();
    int S = scnt; if (S > ECAP) S = ECAP;

    // ---- sort by (weight, pk) ascending ----
    int LEN = 1; while (LEN < S) LEN <<= 1;
    for (int i = S + tid; i < LEN; i += NTH) e2[i] = ~0ull;
    __syncthreads();
    for (int k = 2; k <= LEN; k <<= 1)
        for (int j = k >> 1; j > 0; j >>= 1) {
            for (int t = tid; t < LEN; t += NTH) {
                int l = t ^ j;
                if (l > t) {
                    unsigned long long a = e2[t], b = e2[l];
                    if ((a > b) == ((t & k) == 0)) { e2[t] = b; e2[l] = a; }
                }
            }
            __syncthreads();
        }

    // ---- serial Kruskal on wave 0: labels live in registers (flat, no find) ----
    // lane L, reg r hold label of cid r*64+L. Lookup = uniform reg-select + shfl.
    // Merge (y -> e, e < y): every lane rewrites its 8 labels. No dependent LDS.
    if (tid < 64) {
        int lab[8];
        #pragma unroll
        for (int r = 0; r < 8; ++r) lab[r] = r * 64 + tid;
        int np = 0;
        unsigned long long kk = (S > 0) ? e2[0] : 0ull;
        for (int i = 0; i < S; ++i) {
            int nx = i + 1; if (nx >= S) nx = S - 1;
            unsigned long long kn = e2[nx];           // prefetch next (uniform bcast)
            unsigned pk = (unsigned)(kk & 0x3FFFFull);
            int ra = (int)(pk >> 9), rb = (int)(pk & 511u);
            int t1, t2;
            switch (ra >> 6) {
                case 0: t1 = lab[0]; break; case 1: t1 = lab[1]; break;
                case 2: t1 = lab[2]; break; case 3: t1 = lab[3]; break;
                case 4: t1 = lab[4]; break; case 5: t1 = lab[5]; break;
                case 6: t1 = lab[6]; break; default: t1 = lab[7]; break;
            }
            int la = __shfl(t1, ra & 63);
            switch (rb >> 6) {
                case 0: t2 = lab[0]; break; case 1: t2 = lab[1]; break;
                case 2: t2 = lab[2]; break; case 3: t2 = lab[3]; break;
                case 4: t2 = lab[4]; break; case 5: t2 = lab[5]; break;
                case 6: t2 = lab[6]; break; default: t2 = lab[7]; break;
            }
            int lb = __shfl(t2, rb & 63);
            if (la != lb) {
                int e = la < lb ? la : lb;
                int y = la ^ lb ^ e;
                #pragma unroll
                for (int r = 0; r < 8; ++r) lab[r] = (lab[r] == y) ? e : lab[r];
                if (tid == 0) {
                    float bf = mono2f(bval[y]);       // latency only feeds the store
                    float w  = mono2f((unsigned)(kk >> 18));
                    if (which == 0) { pb[np] = bf; pdd[np] = w; }
                    else            { pb[np] = -w; pdd[np] = -bf; }
                }
                ++np;                                  // uniform across lanes
            }
            kk = kn;
        }
        if (tid == 0) npairs = np;
    }
    __syncthreads();
    const int P = npairs;

    // ---- selection: top-NMAXP by persistence desc (reuse e2) ----
    for (int i = tid; i < SELCAP; i += NTH) {
        unsigned long long kk2 = ~0ull;
        if (i < P) {
            unsigned pm = __float_as_uint(pdd[i] - pb[i]);  // pers > 0 -> monotone
            kk2 = ((unsigned long long)(~pm) << 32) | (unsigned)i;
        }
        e2[i] = kk2;
    }
    __syncthreads();
    int LEN3 = 1; while (LEN3 < P) LEN3 <<= 1;
    for (int k = 2; k <= LEN3; k <<= 1)
        for (int j = k >> 1; j > 0; j >>= 1) {
            for (int t = tid; t < LEN3; t += NTH) {
                int l = t ^ j;
                if (l > t) {
                    unsigned long long a = e2[t], b = e2[l];
                    if ((a > b) == ((t & k) == 0)) { e2[t] = b; e2[l] = a; }
                }
            }
            __syncthreads();
        }

    // ---- write diagram: [32, 2, 100, 2] ----
    float* o = out + (size_t)blk * NMAXP * 2;
    if (tid < NMAXP) {
        float b = 0.f, d = 0.f;
        if (which == 0) {
            if (tid == 0) { b = mono2f(bval[0]); d = ESS_DEATH; }  // essential (min, "inf")
            else {
                int p = tid - 1;
                if (p < P) { int q = (int)(e2[p] & 0xFFFFFFFFull); b = pb[q]; d = pdd[q]; }
            }
        } else {
            if (tid < P) { int q = (int)(e2[tid] & 0xFFFFFFFFull); b = pb[q]; d = pdd[q]; }
        }
        o[tid * 2]     = b;
        o[tid * 2 + 1] = d;
    }
}

extern "C" void kernel_launch(void* const* d_in, const int* in_sizes, int n_in,
                              void* d_out, int out_size, void* d_ws, size_t ws_size,
                              hipStream_t stream) {
    (void)in_sizes; (void)n_in; (void)out_size; (void)d_ws; (void)ws_size;
    const float* x = (const float*)d_in[0];
    float* out = (float*)d_out;
    pd_kernel<<<dim3(64), dim3(NTH), 0, stream>>>(x, out);
}

// Round 7
// 184.220 us; speedup vs baseline: 1.0784x; 1.0784x over previous
//
#include <hip/hip_runtime.h>
#include <math.h>

#define HH 28
#define WW 28
#define NPIX 784
#define MMAX 785
#define NMAXP 100
#define NTH 512
#define BCAP 512       // max basins (theory bound: H1 4-conn <= 393, H0 8-conn <= 196)
#define HSZ 4096
#define HMASK 4095
#define ECAP 2048      // deduped basin-pair edges (random ~470; planar-ish bound ~1200)
#define PCAP 512
#define SELCAP 512
// Essential-death sentinel: must stay FINITE after the harness's bf16
// round-trip (FLT_MAX rounds to +inf in bf16 -> inf-inf=NaN). 1e30 is safe.
#define ESS_DEATH 1e30f

// monotone float<->u32 (totally ordered as unsigned)
__device__ __forceinline__ unsigned f2mono(float f) {
    unsigned u = __float_as_uint(f);
    return (u & 0x80000000u) ? ~u : (u | 0x80000000u);
}
__device__ __forceinline__ float mono2f(unsigned m) {
    unsigned u = (m & 0x80000000u) ? (m ^ 0x80000000u) : ~m;
    return __uint_as_float(u);
}

// neighbors of cell c; nb[k] = -1 if invalid.
// which==0: 8-conn. which==1: 4-conn + virtual boundary node NPIX.
__device__ __forceinline__ int get_nbrs(int c, int which, int* nb) {
    int ci = c / WW;
    int cj = c - ci * WW;
    if (which == 0) {
        const int di[8] = {-1,-1,-1, 0, 0, 1, 1, 1};
        const int dj[8] = {-1, 0, 1,-1, 1,-1, 0, 1};
        #pragma unroll
        for (int k = 0; k < 8; ++k) {
            int ii = ci + di[k], jj = cj + dj[k];
            nb[k] = (ii >= 0 && ii < HH && jj >= 0 && jj < WW) ? (ii * WW + jj) : -1;
        }
        return 8;
    } else {
        const int di[4] = {-1, 1, 0, 0};
        const int dj[4] = { 0, 0,-1, 1};
        #pragma unroll
        for (int k = 0; k < 4; ++k) {
            int ii = ci + di[k], jj = cj + dj[k];
            nb[k] = (ii >= 0 && ii < HH && jj >= 0 && jj < WW) ? (ii * WW + jj) : -1;
        }
        nb[4] = (ci == 0 || ci == HH - 1 || cj == 0 || cj == WW - 1) ? NPIX : -1;
        return 5;
    }
}

// One block per (sample, dim): blk = s*2 + which.
// which==0 -> H0 (8-conn sublevel on x); which==1 -> H1 via superlevel
// (sublevel on -x, 4-conn, virtual -inf boundary node).
__global__ __launch_bounds__(NTH)
void pd_kernel(const float* __restrict__ x, float* __restrict__ out)
{
    const int blk   = blockIdx.x;
    const int s     = blk >> 1;
    const int which = blk & 1;
    const int tid   = threadIdx.x;
    const int M     = NPIX + which;

    __shared__ float vals[MMAX];
    __shared__ int   dA[MMAX];                  // steepest-descent / basin root cell
    __shared__ int   dB[MMAX];                  // jump scratch, then cid at root cells
    __shared__ int   cido[MMAX];                // per-cell compact basin id
    __shared__ unsigned long long rootsSort[BCAP]; // (valmono<<32)|cell -> sorted = cid order
    __shared__ unsigned bval[BCAP];             // basin-min valmono per cid
    __shared__ unsigned hkey[HSZ];              // hash: pk+1 (0 = empty)
    __shared__ unsigned hval[HSZ];              // hash: min weight (monotone u32)
    __shared__ unsigned long long e2[ECAP];     // (wmono<<18)|pk ; reused for selection
    __shared__ float pb[PCAP], pdd[PCAP];       // recorded pairs (output space)
    __shared__ int   bcnt, scnt, npairs;

    if (tid == 0) { bcnt = 0; scnt = 0; npairs = 0; }
    for (int i = tid; i < HSZ; i += NTH) { hkey[i] = 0u; hval[i] = 0xFFFFFFFFu; }
    for (int i = tid; i < BCAP; i += NTH) rootsSort[i] = ~0ull;
    for (int i = tid; i < NPIX; i += NTH) {
        float v = x[s * NPIX + i];
        vals[i] = which ? -v : v;
    }
    if (tid == 0 && which) vals[NPIX] = -INFINITY;
    __syncthreads();

    // ---- steepest-descent pointer: lex-min (val, idx) over {self} U nbrs ----
    for (int i = tid; i < M; i += NTH) {
        int best = i; float bv = vals[i];
        if (i < NPIX) {
            int nb[8];
            int K = get_nbrs(i, which, nb);
            for (int k = 0; k < K; ++k) {
                int n = nb[k]; if (n < 0) continue;
                float vn = vals[n];
                if (vn < bv || (vn == bv && n < best)) { bv = vn; best = n; }
            }
        }
        dA[i] = best;   // == i iff local min (basin root)
    }
    __syncthreads();

    // ---- pointer jumping: 10 compositions -> covers depth 2^10 >= 784 ----
    for (int rnd = 0; rnd < 5; ++rnd) {
        for (int i = tid; i < M; i += NTH) dB[i] = dA[dA[i]];
        __syncthreads();
        for (int i = tid; i < M; i += NTH) dA[i] = dB[dB[i]];
        __syncthreads();
    }

    // ---- collect basin roots, sort by (valmono, cell) -> cid = value order ----
    for (int i = tid; i < M; i += NTH) {
        if (dA[i] == i) {
            int j = atomicAdd(&bcnt, 1);
            if (j < BCAP)
                rootsSort[j] = ((unsigned long long)f2mono(vals[i]) << 32) | (unsigned)i;
        }
    }
    __syncthreads();
    const int B = bcnt;
    int LENB = 1; while (LENB < B) LENB <<= 1;
    for (int k = 2; k <= LENB; k <<= 1)
        for (int j = k >> 1; j > 0; j >>= 1) {
            for (int t = tid; t < LENB; t += NTH) {
                int l = t ^ j;
                if (l > t) {
                    unsigned long long a = rootsSort[t], b = rootsSort[l];
                    if ((a > b) == ((t & k) == 0)) { rootsSort[t] = b; rootsSort[l] = a; }
                }
            }
            __syncthreads();
        }
    for (int b = tid; b < B; b += NTH) {
        unsigned long long v = rootsSort[b];
        if (v != ~0ull) {
            int cell = (int)(v & 0xFFFFFFFFull);
            dB[cell] = b;                       // cid at root cell
            bval[b]  = (unsigned)(v >> 32);
        }
    }
    __syncthreads();
    for (int i = tid; i < M; i += NTH) cido[i] = dB[dA[i]];
    __syncthreads();

    // ---- cross-basin edges -> hash dedup (min weight per basin pair) ----
    for (int c = tid; c < NPIX; c += NTH) {
        float vc = vals[c];
        int bc = cido[c];
        int nb[8];
        int K = get_nbrs(c, which, nb);
        unsigned wm = f2mono(vc);
        for (int k = 0; k < K; ++k) {
            int n = nb[k]; if (n < 0) continue;
            float vn = vals[n];
            if (!(vn < vc || (vn == vc && n < c))) continue;  // emit from higher endpoint
            int bn = cido[n];
            if (bn == bc) continue;
            unsigned c0 = (unsigned)(bc < bn ? bc : bn);
            unsigned c1 = (unsigned)(bc < bn ? bn : bc);
            unsigned pk  = (c0 << 9) | c1;       // cids < 512 -> 18 bits
            unsigned key = pk + 1u;
            unsigned slot = (pk * 0x9E3779B1u) >> 20;  // 12-bit hash
            for (;;) {
                unsigned prev = atomicCAS(&hkey[slot], 0u, key);
                if (prev == 0u || prev == key) { atomicMin(&hval[slot], wm); break; }
                slot = (slot + 1) & HMASK;
            }
        }
    }
    __syncthreads();

    // ---- gather survivors ----
    for (int i = tid; i < HSZ; i += NTH) {
        unsigned key = hkey[i];
        if (key) {
            int j = atomicAdd(&scnt, 1);
            if (j < ECAP)
                e2[j] = ((unsigned long long)hval[i] << 18) | (unsigned long long)(key - 1u);
        }
    }
    __syncthreads();
    int S = scnt; if (S > ECAP) S = ECAP;

    // ---- sort by (weight, pk) ascending ----
    int LEN = 1; while (LEN < S) LEN <<= 1;
    for (int i = S + tid; i < LEN; i += NTH) e2[i] = ~0ull;
    __syncthreads();
    for (int k = 2; k <= LEN; k <<= 1)
        for (int j = k >> 1; j > 0; j >>= 1) {
            for (int t = tid; t < LEN; t += NTH) {
                int l = t ^ j;
                if (l > t) {
                    unsigned long long a = e2[t], b = e2[l];
                    if ((a > b) == ((t & k) == 0)) { e2[t] = b; e2[l] = a; }
                }
            }
            __syncthreads();
        }

    // ---- serial Kruskal on wave 0: labels flat in registers, SCALAR decode ----
    // lane L, reg r hold label of cid r*64+L. Edge keys are wave-uniform but the
    // compiler can't see it (LDS load) -> force SGPRs via readfirstlane so the
    // register-select switch compiles to uniform scalar branches + v_readlane,
    // not divergent exec-mask chains (the R6 regression).
    if (tid < 64) {
        int lab[8];
        #pragma unroll
        for (int r = 0; r < 8; ++r) lab[r] = r * 64 + tid;
        int np = 0;
        unsigned klo = 0u, khi = 0u;
        if (S > 0) {
            unsigned long long k0 = e2[0];
            klo = (unsigned)__builtin_amdgcn_readfirstlane((int)(unsigned)k0);
            khi = (unsigned)__builtin_amdgcn_readfirstlane((int)(unsigned)(k0 >> 32));
        }
        for (int i = 0; i < S; ++i) {
            int nx = i + 1; if (nx >= S) nx = S - 1;
            unsigned long long kn = e2[nx];           // prefetch next edge
            unsigned pk = klo & 0x3FFFFu;
            int ra = (int)(pk >> 9), rb = (int)(pk & 511u);
            int sa = ra >> 6, laneA = ra & 63;
            int sb = rb >> 6, laneB = rb & 63;
            int t1, t2;
            switch (sa) {
                case 0: t1 = lab[0]; break; case 1: t1 = lab[1]; break;
                case 2: t1 = lab[2]; break; case 3: t1 = lab[3]; break;
                case 4: t1 = lab[4]; break; case 5: t1 = lab[5]; break;
                case 6: t1 = lab[6]; break; default: t1 = lab[7]; break;
            }
            int la = __builtin_amdgcn_readlane(t1, laneA);
            switch (sb) {
                case 0: t2 = lab[0]; break; case 1: t2 = lab[1]; break;
                case 2: t2 = lab[2]; break; case 3: t2 = lab[3]; break;
                case 4: t2 = lab[4]; break; case 5: t2 = lab[5]; break;
                case 6: t2 = lab[6]; break; default: t2 = lab[7]; break;
            }
            int lb = __builtin_amdgcn_readlane(t2, laneB);
            if (la != lb) {
                int e = la < lb ? la : lb;
                int y = la ^ lb ^ e;
                #pragma unroll
                for (int r = 0; r < 8; ++r) lab[r] = (lab[r] == y) ? e : lab[r];
                if (tid == 0) {
                    float bf = mono2f(bval[y]);       // latency only feeds the store
                    unsigned wmono = (klo >> 18) | (khi << 14);
                    float w = mono2f(wmono);
                    if (which == 0) { pb[np] = bf; pdd[np] = w; }
                    else            { pb[np] = -w; pdd[np] = -bf; }
                }
                ++np;                                  // uniform across lanes
            }
            klo = (unsigned)__builtin_amdgcn_readfirstlane((int)(unsigned)kn);
            khi = (unsigned)__builtin_amdgcn_readfirstlane((int)(unsigned)(kn >> 32));
        }
        if (tid == 0) npairs = np;
    }
    __syncthreads();
    const int P = npairs;

    // ---- selection: top-NMAXP by persistence desc (reuse e2) ----
    for (int i = tid; i < SELCAP; i += NTH) {
        unsigned long long kk2 = ~0ull;
        if (i < P) {
            unsigned pm = __float_as_uint(pdd[i] - pb[i]);  // pers > 0 -> monotone
            kk2 = ((unsigned long long)(~pm) << 32) | (unsigned)i;
        }
        e2[i] = kk2;
    }
    __syncthreads();
    int LEN3 = 1; while (LEN3 < P) LEN3 <<= 1;
    for (int k = 2; k <= LEN3; k <<= 1)
        for (int j = k >> 1; j > 0; j >>= 1) {
            for (int t = tid; t < LEN3; t += NTH) {
                int l = t ^ j;
                if (l > t) {
                    unsigned long long a = e2[t], b = e2[l];
                    if ((a > b) == ((t & k) == 0)) { e2[t] = b; e2[l] = a; }
                }
            }
            __syncthreads();
        }

    // ---- write diagram: [32, 2, 100, 2] ----
    float* o = out + (size_t)blk * NMAXP * 2;
    if (tid < NMAXP) {
        float b = 0.f, d = 0.f;
        if (which == 0) {
            if (tid == 0) { b = mono2f(bval[0]); d = ESS_DEATH; }  // essential (min, "inf")
            else {
                int p = tid - 1;
                if (p < P) { int q = (int)(e2[p] & 0xFFFFFFFFull); b = pb[q]; d = pdd[q]; }
            }
        } else {
            if (tid < P) { int q = (int)(e2[tid] & 0xFFFFFFFFull); b = pb[q]; d = pdd[q]; }
        }
        o[tid * 2]     = b;
        o[tid * 2 + 1] = d;
    }
}

extern "C" void kernel_launch(void* const* d_in, const int* in_sizes, int n_in,
                              void* d_out, int out_size, void* d_ws, size_t ws_size,
                              hipStream_t stream) {
    (void)in_sizes; (void)n_in; (void)out_size; (void)d_ws; (void)ws_size;
    const float* x = (const float*)d_in[0];
    float* out = (float*)d_out;
    pd_kernel<<<dim3(64), dim3(NTH), 0, stream>>>(x, out);
}

// Round 8
// 177.418 us; speedup vs baseline: 1.1197x; 1.0383x over previous
//
#include <hip/hip_runtime.h>
#include <math.h>

#define HH 28
#define WW 28
#define NPIX 784
#define MMAX 785
#define NMAXP 100
#define NTH 512
#define BCAP 512       // max basins (theory bound: H1 4-conn <= 393, H0 8-conn <= 196)
#define HSZ 4096
#define HMASK 4095
#define ECAP 2048      // deduped basin-pair edges (random ~470; planar-ish bound ~1200)
#define PCAP 512
#define SELCAP 512
// Essential-death sentinel: must stay FINITE after the harness's bf16
// round-trip (FLT_MAX rounds to +inf in bf16 -> inf-inf=NaN). 1e30 is safe.
#define ESS_DEATH 1e30f

// monotone float<->u32 (totally ordered as unsigned)
__device__ __forceinline__ unsigned f2mono(float f) {
    unsigned u = __float_as_uint(f);
    return (u & 0x80000000u) ? ~u : (u | 0x80000000u);
}
__device__ __forceinline__ float mono2f(unsigned m) {
    unsigned u = (m & 0x80000000u) ? (m ^ 0x80000000u) : ~m;
    return __uint_as_float(u);
}

// neighbors of cell c; nb[k] = -1 if invalid.
// which==0: 8-conn. which==1: 4-conn + virtual boundary node NPIX.
__device__ __forceinline__ int get_nbrs(int c, int which, int* nb) {
    int ci = c / WW;
    int cj = c - ci * WW;
    if (which == 0) {
        const int di[8] = {-1,-1,-1, 0, 0, 1, 1, 1};
        const int dj[8] = {-1, 0, 1,-1, 1,-1, 0, 1};
        #pragma unroll
        for (int k = 0; k < 8; ++k) {
            int ii = ci + di[k], jj = cj + dj[k];
            nb[k] = (ii >= 0 && ii < HH && jj >= 0 && jj < WW) ? (ii * WW + jj) : -1;
        }
        return 8;
    } else {
        const int di[4] = {-1, 1, 0, 0};
        const int dj[4] = { 0, 0,-1, 1};
        #pragma unroll
        for (int k = 0; k < 4; ++k) {
            int ii = ci + di[k], jj = cj + dj[k];
            nb[k] = (ii >= 0 && ii < HH && jj >= 0 && jj < WW) ? (ii * WW + jj) : -1;
        }
        nb[4] = (ci == 0 || ci == HH - 1 || cj == 0 || cj == WW - 1) ? NPIX : -1;
        return 5;
    }
}

// One block per (sample, dim): blk = s*2 + which.
// which==0 -> H0 (8-conn sublevel on x); which==1 -> H1 via superlevel
// (sublevel on -x, 4-conn, virtual -inf boundary node).
__global__ __launch_bounds__(NTH)
void pd_kernel(const float* __restrict__ x, float* __restrict__ out)
{
    const int blk   = blockIdx.x;
    const int s     = blk >> 1;
    const int which = blk & 1;
    const int tid   = threadIdx.x;
    const int M     = NPIX + which;

    __shared__ float vals[MMAX];
    __shared__ int   dA[MMAX];                  // steepest-descent / basin root cell
    __shared__ int   dB[MMAX];                  // jump scratch, then cid at root cells
    __shared__ int   cido[MMAX];                // per-cell compact basin id
    __shared__ unsigned long long rootsSort[BCAP]; // (valmono<<32)|cell -> sorted = cid order
    __shared__ unsigned bval[BCAP];             // basin-min valmono per cid
    __shared__ unsigned hkey[HSZ];              // hash: pk+1 (0 = empty)
    __shared__ unsigned hval[HSZ];              // hash: min weight (monotone u32)
    __shared__ unsigned long long e2[ECAP];     // (wmono<<18)|pk ; reused for selection
    __shared__ float pb[PCAP], pdd[PCAP];       // recorded pairs (output space)
    __shared__ int   bcnt, scnt, npairs;

    // Bitonic sort (ascending, u64 keys) with conditional barriers:
    // pass distance j<64 => partners live in the same wave's 64-chunk
    // (thread t owns element t, t+512, ...), so wave-lockstep LDS ordering
    // suffices; only sync when this or the previous pass crossed waves.
    auto bitonic64 = [&](unsigned long long* arr, int LEN) {
        int prevj = 1 << 30;
        for (int k = 2; k <= LEN; k <<= 1)
            for (int j = k >> 1; j > 0; j >>= 1) {
                if (j >= 64 || prevj >= 64) __syncthreads();
                for (int t = tid; t < LEN; t += NTH) {
                    int l = t ^ j;
                    if (l > t) {
                        unsigned long long a = arr[t], b = arr[l];
                        if ((a > b) == ((t & k) == 0)) { arr[t] = b; arr[l] = a; }
                    }
                }
                prevj = j;
            }
        __syncthreads();
    };

    if (tid == 0) { bcnt = 0; scnt = 0; npairs = 0; }
    for (int i = tid; i < HSZ; i += NTH) { hkey[i] = 0u; hval[i] = 0xFFFFFFFFu; }
    for (int i = tid; i < BCAP; i += NTH) rootsSort[i] = ~0ull;
    for (int i = tid; i < NPIX; i += NTH) {
        float v = x[s * NPIX + i];
        vals[i] = which ? -v : v;
    }
    if (tid == 0 && which) vals[NPIX] = -INFINITY;
    __syncthreads();

    // ---- steepest-descent pointer: lex-min (val, idx) over {self} U nbrs ----
    for (int i = tid; i < M; i += NTH) {
        int best = i; float bv = vals[i];
        if (i < NPIX) {
            int nb[8];
            int K = get_nbrs(i, which, nb);
            for (int k = 0; k < K; ++k) {
                int n = nb[k]; if (n < 0) continue;
                float vn = vals[n];
                if (vn < bv || (vn == bv && n < best)) { bv = vn; best = n; }
            }
        }
        dA[i] = best;   // == i iff local min (basin root)
    }
    __syncthreads();

    // ---- pointer jumping: 5 rounds x4 composition -> covers depth 4^5 >= 784 ----
    for (int rnd = 0; rnd < 5; ++rnd) {
        for (int i = tid; i < M; i += NTH) dB[i] = dA[dA[i]];
        __syncthreads();
        for (int i = tid; i < M; i += NTH) dA[i] = dB[dB[i]];
        __syncthreads();
    }

    // ---- collect basin roots, sort by (valmono, cell) -> cid = value order ----
    for (int i = tid; i < M; i += NTH) {
        if (dA[i] == i) {
            int j = atomicAdd(&bcnt, 1);
            if (j < BCAP)
                rootsSort[j] = ((unsigned long long)f2mono(vals[i]) << 32) | (unsigned)i;
        }
    }
    __syncthreads();
    const int B = bcnt;
    int LENB = 1; while (LENB < B) LENB <<= 1;
    bitonic64(rootsSort, LENB);
    for (int b = tid; b < B; b += NTH) {
        unsigned long long v = rootsSort[b];
        if (v != ~0ull) {
            int cell = (int)(v & 0xFFFFFFFFull);
            dB[cell] = b;                       // cid at root cell
            bval[b]  = (unsigned)(v >> 32);
        }
    }
    __syncthreads();
    for (int i = tid; i < M; i += NTH) cido[i] = dB[dA[i]];
    __syncthreads();

    // ---- cross-basin edges -> hash dedup (min weight per basin pair) ----
    for (int c = tid; c < NPIX; c += NTH) {
        float vc = vals[c];
        int bc = cido[c];
        int nb[8];
        int K = get_nbrs(c, which, nb);
        unsigned wm = f2mono(vc);
        for (int k = 0; k < K; ++k) {
            int n = nb[k]; if (n < 0) continue;
            float vn = vals[n];
            if (!(vn < vc || (vn == vc && n < c))) continue;  // emit from higher endpoint
            int bn = cido[n];
            if (bn == bc) continue;
            unsigned c0 = (unsigned)(bc < bn ? bc : bn);
            unsigned c1 = (unsigned)(bc < bn ? bn : bc);
            unsigned pk  = (c0 << 9) | c1;       // cids < 512 -> 18 bits
            unsigned key = pk + 1u;
            unsigned slot = (pk * 0x9E3779B1u) >> 20;  // 12-bit hash
            for (;;) {
                unsigned prev = atomicCAS(&hkey[slot], 0u, key);
                if (prev == 0u || prev == key) { atomicMin(&hval[slot], wm); break; }
                slot = (slot + 1) & HMASK;
            }
        }
    }
    __syncthreads();

    // ---- gather survivors ----
    for (int i = tid; i < HSZ; i += NTH) {
        unsigned key = hkey[i];
        if (key) {
            int j = atomicAdd(&scnt, 1);
            if (j < ECAP)
                e2[j] = ((unsigned long long)hval[i] << 18) | (unsigned long long)(key - 1u);
        }
    }
    __syncthreads();
    int S = scnt; if (S > ECAP) S = ECAP;

    // ---- sort edges by (weight, pk) ascending ----
    int LEN = 1; while (LEN < S) LEN <<= 1;
    for (int i = S + tid; i < LEN; i += NTH) e2[i] = ~0ull;
    bitonic64(e2, LEN);

    // ---- serial Kruskal on wave 0: flat labels in registers, BRANCHLESS decode ----
    // lane L, reg r hold label of cid r*64+L. Edge keys forced to SGPRs via
    // readfirstlane; the 8-way register select is a v_cmp/v_cndmask chain
    // (selector pinned to a VGPR so the compiler cannot emit scalar branch
    // trees -- the R6/R7 cost). Merge relabel likewise branchless.
    if (tid < 64) {
        int lab[8];
        #pragma unroll
        for (int r = 0; r < 8; ++r) lab[r] = r * 64 + tid;
        int np = 0;
        unsigned klo = 0u, khi = 0u;
        if (S > 0) {
            unsigned long long k0 = e2[0];
            klo = (unsigned)__builtin_amdgcn_readfirstlane((int)(unsigned)k0);
            khi = (unsigned)__builtin_amdgcn_readfirstlane((int)(unsigned)(k0 >> 32));
        }
        for (int i = 0; i < S; ++i) {
            int nx = i + 1; if (nx >= S) nx = S - 1;
            unsigned long long kn = e2[nx];           // prefetch next edge
            unsigned pk = klo & 0x3FFFFu;
            int ra = (int)(pk >> 9), rb = (int)(pk & 511u);
            int laneA = ra & 63, laneB = rb & 63;
            int sav = ra >> 6, sbv = rb >> 6;
            asm volatile("" : "+v"(sav));             // pin selector in VGPR
            asm volatile("" : "+v"(sbv));
            int t1 = lab[0], t2 = lab[0];
            #pragma unroll
            for (int r = 1; r < 8; ++r) {
                t1 = (sav == r) ? lab[r] : t1;        // v_cmp + v_cndmask
                t2 = (sbv == r) ? lab[r] : t2;
            }
            int la = __builtin_amdgcn_readlane(t1, laneA);
            int lb = __builtin_amdgcn_readlane(t2, laneB);
            if (la != lb) {
                int e = la < lb ? la : lb;
                int y = la ^ lb ^ e;
                int yv = y;
                asm volatile("" : "+v"(yv));          // branchless relabel
                #pragma unroll
                for (int r = 0; r < 8; ++r) lab[r] = (lab[r] == yv) ? e : lab[r];
                if (tid == 0) {
                    float bf = mono2f(bval[y]);       // latency only feeds the store
                    unsigned wmono = (klo >> 18) | (khi << 14);
                    float w = mono2f(wmono);
                    if (which == 0) { pb[np] = bf; pdd[np] = w; }
                    else            { pb[np] = -w; pdd[np] = -bf; }
                }
                ++np;                                  // uniform across lanes
            }
            klo = (unsigned)__builtin_amdgcn_readfirstlane((int)(unsigned)kn);
            khi = (unsigned)__builtin_amdgcn_readfirstlane((int)(unsigned)(kn >> 32));
        }
        if (tid == 0) npairs = np;
    }
    __syncthreads();
    const int P = npairs;

    // ---- selection: top-NMAXP by persistence desc (reuse e2) ----
    for (int i = tid; i < SELCAP; i += NTH) {
        unsigned long long kk2 = ~0ull;
        if (i < P) {
            unsigned pm = __float_as_uint(pdd[i] - pb[i]);  // pers > 0 -> monotone
            kk2 = ((unsigned long long)(~pm) << 32) | (unsigned)i;
        }
        e2[i] = kk2;
    }
    int LEN3 = 1; while (LEN3 < P) LEN3 <<= 1;
    __syncthreads();
    bitonic64(e2, LEN3);

    // ---- write diagram: [32, 2, 100, 2] ----
    float* o = out + (size_t)blk * NMAXP * 2;
    if (tid < NMAXP) {
        float b = 0.f, d = 0.f;
        if (which == 0) {
            if (tid == 0) { b = mono2f(bval[0]); d = ESS_DEATH; }  // essential (min, "inf")
            else {
                int p = tid - 1;
                if (p < P) { int q = (int)(e2[p] & 0xFFFFFFFFull); b = pb[q]; d = pdd[q]; }
            }
        } else {
            if (tid < P) { int q = (int)(e2[tid] & 0xFFFFFFFFull); b = pb[q]; d = pdd[q]; }
        }
        o[tid * 2]     = b;
        o[tid * 2 + 1] = d;
    }
}

extern "C" void kernel_launch(void* const* d_in, const int* in_sizes, int n_in,
                              void* d_out, int out_size, void* d_ws, size_t ws_size,
                              hipStream_t stream) {
    (void)in_sizes; (void)n_in; (void)out_size; (void)d_ws; (void)ws_size;
    const float* x = (const float*)d_in[0];
    float* out = (float*)d_out;
    pd_kernel<<<dim3(64), dim3(NTH), 0, stream>>>(x, out);
}

// Round 9
// 146.175 us; speedup vs baseline: 1.3591x; 1.2137x over previous
//
#include <hip/hip_runtime.h>
#include <math.h>

#define HH 28
#define WW 28
#define NPIX 784
#define MMAX 785
#define NMAXP 100
#define NTH 512
#define BCAP 512       // max basins (theory bound: H1 4-conn <= 393, H0 8-conn <= 196)
#define HSZ 4096
#define HMASK 4095
#define ECAP 2048      // deduped basin-pair edges (random ~470; planar-ish bound ~1200)
#define PCAP 512
#define SELCAP 512
// Essential-death sentinel: must stay FINITE after the harness's bf16
// round-trip (FLT_MAX rounds to +inf in bf16 -> inf-inf=NaN). 1e30 is safe.
#define ESS_DEATH 1e30f

template<int N> struct IC { static constexpr int v = N; };

// monotone float<->u32 (totally ordered as unsigned)
__device__ __forceinline__ unsigned f2mono(float f) {
    unsigned u = __float_as_uint(f);
    return (u & 0x80000000u) ? ~u : (u | 0x80000000u);
}
__device__ __forceinline__ float mono2f(unsigned m) {
    unsigned u = (m & 0x80000000u) ? (m ^ 0x80000000u) : ~m;
    return __uint_as_float(u);
}

// neighbors of cell c; nb[k] = -1 if invalid.
// which==0: 8-conn. which==1: 4-conn + virtual boundary node NPIX.
__device__ __forceinline__ int get_nbrs(int c, int which, int* nb) {
    int ci = c / WW;
    int cj = c - ci * WW;
    if (which == 0) {
        const int di[8] = {-1,-1,-1, 0, 0, 1, 1, 1};
        const int dj[8] = {-1, 0, 1,-1, 1,-1, 0, 1};
        #pragma unroll
        for (int k = 0; k < 8; ++k) {
            int ii = ci + di[k], jj = cj + dj[k];
            nb[k] = (ii >= 0 && ii < HH && jj >= 0 && jj < WW) ? (ii * WW + jj) : -1;
        }
        return 8;
    } else {
        const int di[4] = {-1, 1, 0, 0};
        const int dj[4] = { 0, 0,-1, 1};
        #pragma unroll
        for (int k = 0; k < 4; ++k) {
            int ii = ci + di[k], jj = cj + dj[k];
            nb[k] = (ii >= 0 && ii < HH && jj >= 0 && jj < WW) ? (ii * WW + jj) : -1;
        }
        nb[4] = (ci == 0 || ci == HH - 1 || cj == 0 || cj == WW - 1) ? NPIX : -1;
        return 5;
    }
}

// One block per (sample, dim): blk = s*2 + which.
// which==0 -> H0 (8-conn sublevel on x); which==1 -> H1 via superlevel
// (sublevel on -x, 4-conn, virtual -inf boundary node).
__global__ __launch_bounds__(NTH)
void pd_kernel(const float* __restrict__ x, float* __restrict__ out)
{
    const int blk   = blockIdx.x;
    const int s     = blk >> 1;
    const int which = blk & 1;
    const int tid   = threadIdx.x;
    const int M     = NPIX + which;

    __shared__ float vals[MMAX];
    __shared__ int   dA[MMAX];                  // steepest-descent / basin root cell
    __shared__ int   dB[MMAX];                  // jump scratch, then cid at root cells
    __shared__ int   cido[MMAX];                // per-cell compact basin id
    __shared__ unsigned long long rootsSort[BCAP]; // (valmono<<32)|cell -> sorted = cid order
    __shared__ unsigned bval[BCAP];             // basin-min valmono per cid
    __shared__ unsigned hkey[HSZ];              // hash: pk+1 (0 = empty)
    __shared__ unsigned hval[HSZ];              // hash: min weight (monotone u32)
    __shared__ unsigned long long e2[ECAP];     // (wmono<<18)|pk ; reused for selection
    __shared__ unsigned long long mrec[PCAP];   // raw merge records (wmono<<32)|y
    __shared__ float pb[PCAP], pdd[PCAP];       // recorded pairs (output space)
    __shared__ int   bcnt, scnt, npairs;

    // Bitonic sort (ascending, u64 keys) with conditional barriers (R8):
    // pass distance j<64 => partners live in the same wave's 64-chunk.
    auto bitonic64 = [&](unsigned long long* arr, int LEN) {
        int prevj = 1 << 30;
        for (int k = 2; k <= LEN; k <<= 1)
            for (int j = k >> 1; j > 0; j >>= 1) {
                if (j >= 64 || prevj >= 64) __syncthreads();
                for (int t = tid; t < LEN; t += NTH) {
                    int l = t ^ j;
                    if (l > t) {
                        unsigned long long a = arr[t], b = arr[l];
                        if ((a > b) == ((t & k) == 0)) { arr[t] = b; arr[l] = a; }
                    }
                }
                prevj = j;
            }
        __syncthreads();
    };

    if (tid == 0) { bcnt = 0; scnt = 0; npairs = 0; }
    for (int i = tid; i < HSZ; i += NTH) { hkey[i] = 0u; hval[i] = 0xFFFFFFFFu; }
    for (int i = tid; i < BCAP; i += NTH) rootsSort[i] = ~0ull;
    for (int i = tid; i < NPIX; i += NTH) {
        float v = x[s * NPIX + i];
        vals[i] = which ? -v : v;
    }
    if (tid == 0 && which) vals[NPIX] = -INFINITY;
    __syncthreads();

    // ---- steepest-descent pointer: lex-min (val, idx) over {self} U nbrs ----
    for (int i = tid; i < M; i += NTH) {
        int best = i; float bv = vals[i];
        if (i < NPIX) {
            int nb[8];
            int K = get_nbrs(i, which, nb);
            for (int k = 0; k < K; ++k) {
                int n = nb[k]; if (n < 0) continue;
                float vn = vals[n];
                if (vn < bv || (vn == bv && n < best)) { bv = vn; best = n; }
            }
        }
        dA[i] = best;   // == i iff local min (basin root)
    }
    __syncthreads();

    // ---- pointer jumping: 5 rounds x4 composition -> covers depth 4^5 >= 784 ----
    for (int rnd = 0; rnd < 5; ++rnd) {
        for (int i = tid; i < M; i += NTH) dB[i] = dA[dA[i]];
        __syncthreads();
        for (int i = tid; i < M; i += NTH) dA[i] = dB[dB[i]];
        __syncthreads();
    }

    // ---- collect basin roots, sort by (valmono, cell) -> cid = value order ----
    for (int i = tid; i < M; i += NTH) {
        if (dA[i] == i) {
            int j = atomicAdd(&bcnt, 1);
            if (j < BCAP)
                rootsSort[j] = ((unsigned long long)f2mono(vals[i]) << 32) | (unsigned)i;
        }
    }
    __syncthreads();
    const int B = bcnt;
    int LENB = 1; while (LENB < B) LENB <<= 1;
    bitonic64(rootsSort, LENB);
    for (int b = tid; b < B; b += NTH) {
        unsigned long long v = rootsSort[b];
        if (v != ~0ull) {
            int cell = (int)(v & 0xFFFFFFFFull);
            dB[cell] = b;                       // cid at root cell
            bval[b]  = (unsigned)(v >> 32);
        }
    }
    __syncthreads();
    for (int i = tid; i < M; i += NTH) cido[i] = dB[dA[i]];
    __syncthreads();

    // ---- cross-basin edges -> hash dedup (min weight per basin pair) ----
    for (int c = tid; c < NPIX; c += NTH) {
        float vc = vals[c];
        int bc = cido[c];
        int nb[8];
        int K = get_nbrs(c, which, nb);
        unsigned wm = f2mono(vc);
        for (int k = 0; k < K; ++k) {
            int n = nb[k]; if (n < 0) continue;
            float vn = vals[n];
            if (!(vn < vc || (vn == vc && n < c))) continue;  // emit from higher endpoint
            int bn = cido[n];
            if (bn == bc) continue;
            unsigned c0 = (unsigned)(bc < bn ? bc : bn);
            unsigned c1 = (unsigned)(bc < bn ? bn : bc);
            unsigned pk  = (c0 << 9) | c1;       // cids < 512 -> 18 bits
            unsigned key = pk + 1u;
            unsigned slot = (pk * 0x9E3779B1u) >> 20;  // 12-bit hash
            for (;;) {
                unsigned prev = atomicCAS(&hkey[slot], 0u, key);
                if (prev == 0u || prev == key) { atomicMin(&hval[slot], wm); break; }
                slot = (slot + 1) & HMASK;
            }
        }
    }
    __syncthreads();

    // ---- gather survivors ----
    for (int i = tid; i < HSZ; i += NTH) {
        unsigned key = hkey[i];
        if (key) {
            int j = atomicAdd(&scnt, 1);
            if (j < ECAP)
                e2[j] = ((unsigned long long)hval[i] << 18) | (unsigned long long)(key - 1u);
        }
    }
    __syncthreads();
    int S = scnt; if (S > ECAP) S = ECAP;

    // ---- sort edges by (weight, pk) ascending; LEN>=4 so tail lanes see pads ----
    int LEN = 4; while (LEN < S) LEN <<= 1;
    for (int i = S + tid; i < LEN; i += NTH) e2[i] = ~0ull;
    bitonic64(e2, LEN);

    // ---- serial Kruskal on wave 0: 4-wide speculative, registers + SALU ----
    // lane L holds labels of cids {r*64+L}. Edges cached lane-resident (one
    // ds_read_b64 per 64 edges, fields via v_readlane with scalar lane). Per
    // 4-edge block: select 8 endpoint labels from pre-block state (VALU
    // cndmask tree, depth 2-3), resolve sequentially in SALU with cascading
    // fix-ups (la'=(la==y_k)?e_k:la in merge order == exact sequential
    // semantics), relabel regs once per actual merge, record raw (wmono,y)
    // via fire-and-forget ds_write (bval lookup deferred to a parallel pass).
    auto kruskal = [&](auto icreg) {
        constexpr int NREG = decltype(icreg)::v;
        int lab[NREG];
        #pragma unroll
        for (int r = 0; r < NREG; ++r) lab[r] = r * 64 + tid;
        int np = 0;
        const int S4 = (S + 3) & ~3;
        unsigned long long ecache = 0ull;
        for (int base = 0; base < S4; base += 4) {
            if ((base & 63) == 0) {
                int idx = base + tid;
                idx = idx < LEN ? idx : (LEN - 1);
                ecache = e2[idx];
            }
            unsigned klo[4], khi[4];
            int la[4], lb[4];
            #pragma unroll
            for (int t = 0; t < 4; ++t) {
                int lane = (base & 63) + t;
                klo[t] = (unsigned)__builtin_amdgcn_readlane((int)(unsigned)ecache, lane);
                khi[t] = (unsigned)__builtin_amdgcn_readlane((int)(unsigned)(ecache >> 32), lane);
                unsigned pk  = klo[t] & 0x3FFFFu;
                unsigned raa = pk >> 9, rbb = pk & 511u;
                int sa = (int)(raa >> 6), sb = (int)(rbb >> 6);
                asm volatile("" : "+v"(sa), "+v"(sb));   // force cndmask tree, not branches
                int g1, g2;
                if constexpr (NREG == 4) {
                    int a1 = (sa & 1) ? lab[1] : lab[0];
                    int b1 = (sa & 1) ? lab[3] : lab[2];
                    g1 = (sa & 2) ? b1 : a1;
                    int a2 = (sb & 1) ? lab[1] : lab[0];
                    int b2 = (sb & 1) ? lab[3] : lab[2];
                    g2 = (sb & 2) ? b2 : a2;
                } else {
                    int a1 = (sa & 1) ? lab[1] : lab[0];
                    int b1 = (sa & 1) ? lab[3] : lab[2];
                    int c1 = (sa & 1) ? lab[5] : lab[4];
                    int d1 = (sa & 1) ? lab[7] : lab[6];
                    int e1 = (sa & 2) ? b1 : a1;
                    int f1 = (sa & 2) ? d1 : c1;
                    g1 = (sa & 4) ? f1 : e1;
                    int a2 = (sb & 1) ? lab[1] : lab[0];
                    int b2 = (sb & 1) ? lab[3] : lab[2];
                    int c2 = (sb & 1) ? lab[5] : lab[4];
                    int d2 = (sb & 1) ? lab[7] : lab[6];
                    int e2v = (sb & 2) ? b2 : a2;
                    int f2 = (sb & 2) ? d2 : c2;
                    g2 = (sb & 4) ? f2 : e2v;
                }
                la[t] = __builtin_amdgcn_readlane(g1, (int)(raa & 63u));
                lb[t] = __builtin_amdgcn_readlane(g2, (int)(rbb & 63u));
            }
            // sequential resolve with cascading fix-ups (SALU; uniform values)
            int ys[4], es[4];
            #pragma unroll
            for (int t = 0; t < 4; ++t) {
                int A = la[t], Bv = lb[t];
                #pragma unroll
                for (int k = 0; k < t; ++k) {
                    A  = (A  == ys[k]) ? es[k] : A;
                    Bv = (Bv == ys[k]) ? es[k] : Bv;
                }
                int mn = A < Bv ? A : Bv;
                int mx = A ^ Bv ^ mn;
                es[t] = mn;
                ys[t] = (A != Bv) ? mx : -1;
            }
            // parallel record: lane t handles edge t's merge (fire-and-forget)
            int myY = -1; unsigned myW = 0u; int myOff = 0;
            int off = 0;
            #pragma unroll
            for (int t = 0; t < 4; ++t) {
                bool mg = ys[t] >= 0;
                if (tid == t && mg) {
                    myY = ys[t];
                    myW = (klo[t] >> 18) | (khi[t] << 14);
                    myOff = np + off;
                }
                off += mg ? 1 : 0;
            }
            if (myY >= 0 && myOff < PCAP)
                mrec[myOff] = ((unsigned long long)myW << 32) | (unsigned)myY;
            np += off;
            // relabel registers per actual merge (uniform branch)
            #pragma unroll
            for (int t = 0; t < 4; ++t) {
                if (ys[t] >= 0) {
                    #pragma unroll
                    for (int r = 0; r < NREG; ++r)
                        lab[r] = (lab[r] == ys[t]) ? es[t] : lab[r];
                }
            }
        }
        if (tid == 0) npairs = (np < PCAP) ? np : PCAP;
    };
    if (tid < 64) {
        if (B <= 256) kruskal(IC<4>{});
        else          kruskal(IC<8>{});
    }
    __syncthreads();
    const int P = npairs;

    // ---- materialize pairs from raw merge records (parallel) ----
    for (int i = tid; i < P; i += NTH) {
        unsigned long long m = mrec[i];
        int y = (int)(m & 0xFFFFFFFFull);
        float w  = mono2f((unsigned)(m >> 32));
        float bf = mono2f(bval[y]);
        if (which == 0) { pb[i] = bf; pdd[i] = w; }
        else            { pb[i] = -w; pdd[i] = -bf; }
    }
    __syncthreads();

    // ---- selection: top-NMAXP by persistence desc (reuse e2) ----
    for (int i = tid; i < SELCAP; i += NTH) {
        unsigned long long kk2 = ~0ull;
        if (i < P) {
            unsigned pm = __float_as_uint(pdd[i] - pb[i]);  // pers > 0 -> monotone
            kk2 = ((unsigned long long)(~pm) << 32) | (unsigned)i;
        }
        e2[i] = kk2;
    }
    int LEN3 = 1; while (LEN3 < P) LEN3 <<= 1;
    __syncthreads();
    bitonic64(e2, LEN3);

    // ---- write diagram: [32, 2, 100, 2] ----
    float* o = out + (size_t)blk * NMAXP * 2;
    if (tid < NMAXP) {
        float b = 0.f, d = 0.f;
        if (which == 0) {
            if (tid == 0) { b = mono2f(bval[0]); d = ESS_DEATH; }  // essential (min, "inf")
            else {
                int p = tid - 1;
                if (p < P) { int q = (int)(e2[p] & 0xFFFFFFFFull); b = pb[q]; d = pdd[q]; }
            }
        } else {
            if (tid < P) { int q = (int)(e2[tid] & 0xFFFFFFFFull); b = pb[q]; d = pdd[q]; }
        }
        o[tid * 2]     = b;
        o[tid * 2 + 1] = d;
    }
}

extern "C" void kernel_launch(void* const* d_in, const int* in_sizes, int n_in,
                              void* d_out, int out_size, void* d_ws, size_t ws_size,
                              hipStream_t stream) {
    (void)in_sizes; (void)n_in; (void)out_size; (void)d_ws; (void)ws_size;
    const float* x = (const float*)d_in[0];
    float* out = (float*)d_out;
    pd_kernel<<<dim3(64), dim3(NTH), 0, stream>>>(x, out);
}